// Round 2
// baseline (238.913 us; speedup 1.0000x reference)
//
#include <hip/hip_runtime.h>

// LIF forward: X [B, T, N] fp32 -> spikes [B, T, N] fp32
// B=128, T=32, N=8192.
//   mem = mem + (x - mem)/2 ; spike = (mem-1 > 0) ; mem = spike ? 0 : mem
// Memory-bound (~218 MB effective HBM traffic -> ~35 us floor).
// R1: naive unroll gave VGPR=24, ~2 loads in flight, latency-bound 85 us.
// R2: explicit double-buffered CHUNK=8 prefetch -> 8 outstanding 1KB
//     loads/wave to cover ~900-cycle HBM latency.

#define T_STEPS 32
#define CHUNK 8
#define NCHUNK (T_STEPS / CHUNK)

__global__ __launch_bounds__(256) void lif_fwd_kernel(
    const float4* __restrict__ X, float4* __restrict__ out,
    int N4 /* N/4 */, int TN4 /* T*N/4 */)
{
    const int idx = blockIdx.x * blockDim.x + threadIdx.x;  // over B * N4
    const int b = idx / N4;
    const int n = idx - b * N4;
    const size_t base = (size_t)b * (size_t)TN4 + (size_t)n;

    const float4* __restrict__ px = X + base;
    float4* __restrict__ po = out + base;

    float m0 = 0.f, m1 = 0.f, m2 = 0.f, m3 = 0.f;

    float4 buf[2][CHUNK];

    // prime: issue first 8 loads back-to-back
#pragma unroll
    for (int j = 0; j < CHUNK; ++j)
        buf[0][j] = px[(size_t)j * (size_t)N4];

#pragma unroll
    for (int c = 0; c < NCHUNK; ++c) {
        const int cb = c & 1;

        // prefetch next chunk while computing this one
        if (c + 1 < NCHUNK) {
#pragma unroll
            for (int j = 0; j < CHUNK; ++j)
                buf[cb ^ 1][j] = px[(size_t)((c + 1) * CHUNK + j) * (size_t)N4];
        }

#pragma unroll
        for (int j = 0; j < CHUNK; ++j) {
            const float4 x = buf[cb][j];

            // exact reference order: mem += (x - mem) * 0.5 ; threshold 1.0
            m0 = m0 + (x.x - m0) * 0.5f;
            m1 = m1 + (x.y - m1) * 0.5f;
            m2 = m2 + (x.z - m2) * 0.5f;
            m3 = m3 + (x.w - m3) * 0.5f;

            float4 s;
            s.x = (m0 - 1.0f > 0.0f) ? 1.0f : 0.0f;
            s.y = (m1 - 1.0f > 0.0f) ? 1.0f : 0.0f;
            s.z = (m2 - 1.0f > 0.0f) ? 1.0f : 0.0f;
            s.w = (m3 - 1.0f > 0.0f) ? 1.0f : 0.0f;

            m0 = (s.x != 0.0f) ? 0.0f : m0;
            m1 = (s.y != 0.0f) ? 0.0f : m1;
            m2 = (s.z != 0.0f) ? 0.0f : m2;
            m3 = (s.w != 0.0f) ? 0.0f : m3;

            po[(size_t)(c * CHUNK + j) * (size_t)N4] = s;
        }
    }
}

extern "C" void kernel_launch(void* const* d_in, const int* in_sizes, int n_in,
                              void* d_out, int out_size, void* d_ws, size_t ws_size,
                              hipStream_t stream) {
    const float4* X = (const float4*)d_in[0];
    float4* out = (float4*)d_out;

    const int N = 8192;
    const int T = T_STEPS;
    const int total = in_sizes[0];          // B*T*N
    const int B = total / (T * N);          // 128

    const int N4 = N / 4;                   // 2048
    const int TN4 = T * N4;                 // 65536
    const int threads = B * N4;             // 262144

    const int block = 256;
    const int grid = (threads + block - 1) / block;  // 1024

    lif_fwd_kernel<<<grid, block, 0, stream>>>(X, out, N4, TN4);
}

// Round 3
// 225.442 us; speedup vs baseline: 1.0598x; 1.0598x over previous
//
#include <hip/hip_runtime.h>

// LIF forward: X [B, T, N] fp32 -> spikes [B, T, N] fp32
// B=128, T=32, N=8192.
//   mem = mem + (x - mem)/2 ; spike = (mem-1 > 0) ; mem = spike ? 0 : mem
// Memory-bound (~200 MB effective HBM traffic -> ~32 us floor).
// R1: float4 naive, VGPR=24, 85 us, 2.5 TB/s.
// R2: explicit double-buffer -> compiler collapsed it, neutral. Root cause
//     found: float4 grid (4096 waves) caps occupancy at 50% of 8192 slots.
// R3: float2 -> 8192 waves = 100% occupancy; rely on TLP not ILP.
//     32 waves/CU x 512B outstanding = 16 KB/CU > 9.2 KB BW*latency product.

#define T_STEPS 32

__global__ __launch_bounds__(256) void lif_fwd_kernel(
    const float2* __restrict__ X, float2* __restrict__ out,
    int N2 /* N/2 */, int TN2 /* T*N/2 */)
{
    const int idx = blockIdx.x * blockDim.x + threadIdx.x;  // over B * N2
    const int b = idx / N2;
    const int n = idx - b * N2;
    const size_t base = (size_t)b * (size_t)TN2 + (size_t)n;

    const float2* __restrict__ px = X + base;
    float2* __restrict__ po = out + base;

    float m0 = 0.f, m1 = 0.f;

    // one-step prefetch: keep next load in flight during current compute
    float2 x = px[0];

#pragma unroll
    for (int t = 0; t < T_STEPS; ++t) {
        float2 xn;
        if (t + 1 < T_STEPS) xn = px[(size_t)(t + 1) * (size_t)N2];

        // exact reference order: mem += (x - mem) * 0.5 ; threshold 1.0
        m0 = m0 + (x.x - m0) * 0.5f;
        m1 = m1 + (x.y - m1) * 0.5f;

        float2 s;
        s.x = (m0 - 1.0f > 0.0f) ? 1.0f : 0.0f;
        s.y = (m1 - 1.0f > 0.0f) ? 1.0f : 0.0f;

        m0 = (s.x != 0.0f) ? 0.0f : m0;
        m1 = (s.y != 0.0f) ? 0.0f : m1;

        po[(size_t)t * (size_t)N2] = s;
        x = xn;
    }
}

extern "C" void kernel_launch(void* const* d_in, const int* in_sizes, int n_in,
                              void* d_out, int out_size, void* d_ws, size_t ws_size,
                              hipStream_t stream) {
    const float2* X = (const float2*)d_in[0];
    float2* out = (float2*)d_out;

    const int N = 8192;
    const int T = T_STEPS;
    const int total = in_sizes[0];          // B*T*N
    const int B = total / (T * N);          // 128

    const int N2 = N / 2;                   // 4096
    const int TN2 = T * N2;                 // 131072
    const int threads = B * N2;             // 524288

    const int block = 256;
    const int grid = (threads + block - 1) / block;  // 2048

    lif_fwd_kernel<<<grid, block, 0, stream>>>(X, out, N2, TN2);
}